// Round 4
// baseline (513.389 us; speedup 1.0000x reference)
//
#include <hip/hip_runtime.h>
#include <hip/hip_bf16.h>
#include <stdint.h>

#define Bn 4
#define Sn 2048
#define Dn 1024
#define Hn 16
#define HDn 64
#define Mn (Bn * Sn)  // 8192
#define PS 44         // P_lds row stride (elems), conflict-free (R3: 0 conflicts)

typedef __attribute__((ext_vector_type(8))) __bf16 bf16x8;
typedef __attribute__((ext_vector_type(4))) __bf16 bf16x4;
typedef __attribute__((ext_vector_type(4))) float f32x4;

#if __has_builtin(__builtin_amdgcn_exp2f)
#define EXP2F(x) __builtin_amdgcn_exp2f(x)
#else
#define EXP2F(x) exp2f(x)
#endif

typedef __attribute__((address_space(1))) unsigned int as1_uint;
typedef __attribute__((address_space(3))) unsigned int as3_uint;

__device__ __forceinline__ void gld_lds16(const void* g, void* l) {
  __builtin_amdgcn_global_load_lds((const as1_uint*)g, (as3_uint*)l, 16, 0, 0);
}

// ------------- fused f32 -> bf16 conversion for all 7 arrays --------------
// dst order: Wq,Wk,Wv,Wo (4x DD), query,key,value (3x MD) - contiguous in ws
struct CvtArgs {
  const float* src[7];
};
__constant__ const size_t kGb[8] = {0,      131072,  262144,  393216,
                                    524288, 1572864, 2621440, 3670016};

__global__ __launch_bounds__(256) void cvt_all(CvtArgs a, __bf16* __restrict__ dst) {
  size_t i = (size_t)blockIdx.x * 256 + threadIdx.x;
  if (i >= 3670016) return;
  int s = 0;
#pragma unroll
  for (int k = 1; k < 7; k++) s += (i >= kGb[k]) ? 1 : 0;
  const float4* sp = (const float4*)a.src[s] + 2 * (i - kGb[s]);
  float4 x = sp[0], y = sp[1];
  bf16x8 o;
  o[0] = (__bf16)x.x; o[1] = (__bf16)x.y; o[2] = (__bf16)x.z; o[3] = (__bf16)x.w;
  o[4] = (__bf16)y.x; o[5] = (__bf16)y.y; o[6] = (__bf16)y.z; o[7] = (__bf16)y.w;
  *(bf16x8*)(dst + 8 * i) = o;
}

// ------------- 128x128 tile GEMM, C = A @ B^T (+bias)*scale --------------
// MODE 0: bf16 row-major out [M x Dn], col-indexed bias.
// MODE 1: f32 row-major out [M x Dn], col-indexed bias.
// MODE 3: bf16 row-major out [M x Mn] (N=8192), ROW-indexed bias (V^T proj).
template <int MODE>
__device__ __forceinline__ void gemm128_body(const __bf16* __restrict__ A,
                                             const __bf16* __restrict__ Bw,
                                             const float* __restrict__ bias,
                                             void* __restrict__ Cout, int m0, int n0,
                                             float scale) {
  __shared__ __align__(16) __bf16 lA[128 * 32];
  __shared__ __align__(16) __bf16 lB[128 * 32];
  const int tid = threadIdx.x;
  const int wave = tid >> 6, lane = tid & 63, quad = lane >> 4, l15 = lane & 15;
  const int wm = wave >> 1, wn = wave & 1;
  f32x4 acc[4][4] = {};
  const char* Ab = (const char*)(A + (size_t)m0 * Dn);
  const char* Bb = (const char*)(Bw + (size_t)n0 * Dn);
  char* lAc = (char*)lA;
  char* lBc = (char*)lB;
  const int o0 = tid * 16, o1 = o0 + 4096;
  const int r0 = o0 >> 6, c0 = o0 & 63;
  const int r1 = o1 >> 6, c1 = o1 & 63;

  for (int k0 = 0; k0 < Dn; k0 += 32) {
    __syncthreads();
    gld_lds16(Ab + (size_t)r0 * 2048 + k0 * 2 + c0, lAc + o0);
    gld_lds16(Ab + (size_t)r1 * 2048 + k0 * 2 + c1, lAc + o1);
    gld_lds16(Bb + (size_t)r0 * 2048 + k0 * 2 + c0, lBc + o0);
    gld_lds16(Bb + (size_t)r1 * 2048 + k0 * 2 + c1, lBc + o1);
    __syncthreads();
    bf16x8 af[4], bfv[4];
#pragma unroll
    for (int i = 0; i < 4; i++)
      af[i] = *(const bf16x8*)(lA + (wm * 64 + i * 16 + l15) * 32 + quad * 8);
#pragma unroll
    for (int t = 0; t < 4; t++)
      bfv[t] = *(const bf16x8*)(lB + (wn * 64 + t * 16 + l15) * 32 + quad * 8);
#pragma unroll
    for (int i = 0; i < 4; i++)
#pragma unroll
      for (int t = 0; t < 4; t++)
        acc[i][t] = __builtin_amdgcn_mfma_f32_16x16x32_bf16(af[i], bfv[t], acc[i][t], 0, 0, 0);
  }
  // epilogue: C/D layout col=lane&15, row=quad*4+reg (m89-verified)
#pragma unroll
  for (int i = 0; i < 4; i++) {
    const int rowb = m0 + wm * 64 + i * 16 + quad * 4;
#pragma unroll
    for (int t = 0; t < 4; t++) {
      const int col = n0 + wn * 64 + t * 16 + l15;
      if (MODE == 3) {
        // row-indexed bias; out stride Mn; coalesced (lanes -> consecutive col)
#pragma unroll
        for (int r = 0; r < 4; r++) {
          float v = acc[i][t][r] + bias[rowb + r];
          ((__bf16*)Cout)[(size_t)(rowb + r) * Mn + col] = (__bf16)v;
        }
      } else {
        const float bb = bias[col];
#pragma unroll
        for (int r = 0; r < 4; r++) {
          float v = (acc[i][t][r] + bb) * scale;
          if (MODE == 1)
            ((float*)Cout)[(size_t)(rowb + r) * Dn + col] = v;
          else
            ((__bf16*)Cout)[(size_t)(rowb + r) * Dn + col] = (__bf16)v;
        }
      }
    }
  }
}

__global__ __launch_bounds__(256, 3) void qkv_gemm(
    const __bf16* __restrict__ X, const __bf16* __restrict__ W,
    const float* __restrict__ bq, const float* __restrict__ bk,
    const float* __restrict__ bv, __bf16* __restrict__ out) {
  const int z = blockIdx.z;
  const size_t MD = (size_t)Mn * Dn, DD = (size_t)Dn * Dn;
  if (z == 0) {
    // fold softmax scale (1/8)*log2(e) into Q so scores are in exp2 domain
    gemm128_body<0>(X, W, bq, out, blockIdx.y * 128, blockIdx.x * 128,
                    0.18033688011112042f);
  } else if (z == 1) {
    gemm128_body<0>(X + MD, W + DD, bk, out + MD, blockIdx.y * 128, blockIdx.x * 128, 1.0f);
  } else {
    // V^T projection: C' = Wv (.) Xv^T -> Vt'[d][token], coalesced stores
    gemm128_body<3>(W + 2 * DD, X + 2 * MD, bv, out + 2 * MD, blockIdx.x * 128,
                    blockIdx.y * 128, 1.0f);
  }
}

__global__ __launch_bounds__(256, 3) void out_gemm(const __bf16* __restrict__ A,
                                                   const __bf16* __restrict__ W,
                                                   const float* __restrict__ bo,
                                                   float* __restrict__ out) {
  gemm128_body<1>(A, W, bo, out, blockIdx.y * 128, blockIdx.x * 128, 1.0f);
}

// ---------------- flash attention, one wave = 64 q-rows -------------------
// S^T = K*Q^T (operand-swapped, R3-verified, 0 LDS conflicts). kv-split over
// grid.z: max-free softmax makes O/li partials additive. Partial O stored f32
// + li per (b,h,q); reduce_norm combines and normalizes.
// Register diet for 3 waves/SIMD: single-buffered kf/vf, tk processed
// serially, next-kstep kf load placed in the ds_write->ds_read shadow.
__global__ __launch_bounds__(256, 3) void flash_attn(const __bf16* __restrict__ Q,
                                                     const __bf16* __restrict__ K,
                                                     const __bf16* __restrict__ Vt,
                                                     float* __restrict__ Opart,
                                                     float* __restrict__ Lpart) {
  __shared__ __align__(16) __bf16 plds[4][64 * PS];
  const int tid = threadIdx.x;
  const int wave = tid >> 6, lane = tid & 63, quad = lane >> 4, l15 = lane & 15;
  const int b = blockIdx.y >> 4, h = blockIdx.y & 15;
  const int q0 = blockIdx.x * 256 + wave * 64;
  const int split = blockIdx.z, nsp = gridDim.z;
  const int kspan = Sn / nsp, kbeg = split * kspan;
  const __bf16* Qb = Q + ((size_t)b * Sn) * Dn + h * HDn;
  const __bf16* Kb = K + ((size_t)b * Sn) * Dn + h * HDn;
  const __bf16* Vtb = Vt + (size_t)h * HDn * Mn + b * Sn;  // Vt'[d][token]
  __bf16* myP = &plds[wave][0];

  // resident Q fragments, MFMA B-operand of S^T: B[k=d][n=q]
  bf16x8 qf[4][2];
#pragma unroll
  for (int iq = 0; iq < 4; iq++)
#pragma unroll
    for (int s = 0; s < 2; s++)
      qf[iq][s] = *(const bf16x8*)(Qb + (size_t)(q0 + iq * 16 + l15) * Dn + s * 32 + quad * 8);

  f32x4 O[4][4] = {};  // O^T acc: [mc][iq], col=q=l15, row=c=quad*4+r
  float li[4] = {};

  // preload first kstep's K fragments
  bf16x8 kf[2][2];
#pragma unroll
  for (int tk = 0; tk < 2; tk++)
#pragma unroll
    for (int s = 0; s < 2; s++)
      kf[tk][s] = *(const bf16x8*)(Kb + (size_t)(kbeg + tk * 16 + l15) * Dn + s * 32 + quad * 8);

  for (int kt = 0; kt < kspan / 32; kt++) {
    const int key0 = kbeg + kt * 32;
    // V fragments (A-operand of PV): 16B contiguous from Vt'
    bf16x8 vf[4];
#pragma unroll
    for (int mc = 0; mc < 4; mc++)
      vf[mc] = *(const bf16x8*)(Vtb + (size_t)(mc * 16 + l15) * Mn + key0 + quad * 8);
    // S^T tiles, tk processed serially (halves live sa registers)
#pragma unroll
    for (int tk = 0; tk < 2; tk++) {
      f32x4 sa[4];
#pragma unroll
      for (int iq = 0; iq < 4; iq++) {
        f32x4 z = {0.f, 0.f, 0.f, 0.f};
        z = __builtin_amdgcn_mfma_f32_16x16x32_bf16(kf[tk][0], qf[iq][0], z, 0, 0, 0);
        z = __builtin_amdgcn_mfma_f32_16x16x32_bf16(kf[tk][1], qf[iq][1], z, 0, 0, 0);
        sa[iq] = z;
      }
      // P = exp2(S^T): 4 consecutive keys per lane -> packed b64 store
#pragma unroll
      for (int iq = 0; iq < 4; iq++) {
        bf16x4 pk;
#pragma unroll
        for (int r = 0; r < 4; r++) {
          float p = EXP2F(sa[iq][r]);
          li[iq] += p;
          pk[r] = (__bf16)p;
        }
        *(bf16x4*)(myP + (iq * 16 + l15) * PS + tk * 16 + quad * 4) = pk;
      }
    }
    // next kstep's K fragments: issued in the ds_write->ds_read shadow
    if (kt + 1 < kspan / 32) {
      const int kn = key0 + 32;
#pragma unroll
      for (int tk = 0; tk < 2; tk++)
#pragma unroll
        for (int s = 0; s < 2; s++)
          kf[tk][s] =
              *(const bf16x8*)(Kb + (size_t)(kn + tk * 16 + l15) * Dn + s * 32 + quad * 8);
    }
    // PV: O^T += Vt-frag (A) x P-frag (B); B read back along contiguous keys
#pragma unroll
    for (int iq = 0; iq < 4; iq++) {
      bf16x4 plo = *(const bf16x4*)(myP + (iq * 16 + l15) * PS + quad * 8);
      bf16x4 phi = *(const bf16x4*)(myP + (iq * 16 + l15) * PS + quad * 8 + 4);
      bf16x8 pf = __builtin_shufflevector(plo, phi, 0, 1, 2, 3, 4, 5, 6, 7);
#pragma unroll
      for (int mc = 0; mc < 4; mc++)
        O[mc][iq] = __builtin_amdgcn_mfma_f32_16x16x32_bf16(vf[mc], pf, O[mc][iq], 0, 0, 0);
    }
  }
  // li partial: reduce across quads (keys are quad-split), store from quad 0
#pragma unroll
  for (int iq = 0; iq < 4; iq++) {
    float s = li[iq];
    s += __shfl_xor(s, 16);
    s += __shfl_xor(s, 32);
    li[iq] = s;
  }
  if (quad == 0) {
#pragma unroll
    for (int iq = 0; iq < 4; iq++)
      Lpart[(size_t)split * (Bn * Hn * Sn) + ((size_t)(b * Hn + h)) * Sn + q0 + iq * 16 + l15] =
          li[iq];
  }
  // store raw O^T partials: 4 consecutive d per lane -> f32x4 stores
  float* Ob = Opart + (size_t)split * Mn * Dn;
#pragma unroll
  for (int mc = 0; mc < 4; mc++)
#pragma unroll
    for (int iq = 0; iq < 4; iq++)
      *(f32x4*)(Ob + ((size_t)b * Sn + q0 + iq * 16 + l15) * Dn + h * HDn + mc * 16 + quad * 4) =
          O[mc][iq];
}

// ------------- combine kv-split partials, normalize, cast bf16 ------------
__global__ __launch_bounds__(256) void reduce_norm(const float* __restrict__ O,
                                                   const float* __restrict__ L, int nsplit,
                                                   __bf16* __restrict__ Attn) {
  const int m = blockIdx.x, t = threadIdx.x;
  const int d0 = t * 4, h = d0 >> 6;
  const int b = m >> 11, q = m & 2047;
  const size_t lio = ((size_t)(b * Hn + h)) * Sn + q;
  float l = L[lio];
  f32x4 o = *(const f32x4*)(O + (size_t)m * Dn + d0);
  if (nsplit == 2) {
    l += L[(size_t)Bn * Hn * Sn + lio];
    f32x4 o2 = *(const f32x4*)(O + (size_t)Mn * Dn + (size_t)m * Dn + d0);
    o += o2;
  }
  const float inv = 1.0f / l;
  bf16x4 r;
#pragma unroll
  for (int k = 0; k < 4; k++) r[k] = (__bf16)(o[k] * inv);
  *(bf16x4*)(Attn + (size_t)m * Dn + d0) = r;
}

extern "C" void kernel_launch(void* const* d_in, const int* in_sizes, int n_in,
                              void* d_out, int out_size, void* d_ws, size_t ws_size,
                              hipStream_t stream) {
  const float* bq = (const float*)d_in[4];
  const float* bk = (const float*)d_in[6];
  const float* bv = (const float*)d_in[8];
  const float* bo = (const float*)d_in[10];

  const size_t MD = (size_t)Mn * Dn;  // 8,388,608
  const size_t DD = (size_t)Dn * Dn;  // 1,048,576
  const size_t MB = 1ull << 20;
  // ws layout: W bf16 [0,8MB) | X bf16 [8,56) | QKV bf16 [56,104) | Attn [104,120)
  __bf16* Wbf  = (__bf16*)d_ws;
  __bf16* Xbf  = (__bf16*)((char*)d_ws + 8 * MB);
  __bf16* QKV  = (__bf16*)((char*)d_ws + 56 * MB);
  __bf16* Attn = (__bf16*)((char*)d_ws + 104 * MB);
  // kv-split partials: nsplit=2 needs [120,186)MB; fallback aliases dead X
  const int nsplit = (ws_size >= 186 * MB) ? 2 : 1;
  float* Lpart;
  float* Opart;
  if (nsplit == 2) {
    Lpart = (float*)((char*)d_ws + 120 * MB);
    Opart = (float*)((char*)d_ws + 121 * MB);
  } else {
    Lpart = (float*)((char*)d_ws + 8 * MB);  // X is dead after qkv_gemm
    Opart = (float*)((char*)d_ws + 9 * MB);
  }

  CvtArgs ca;
  ca.src[0] = (const float*)d_in[3];  // Wq
  ca.src[1] = (const float*)d_in[5];  // Wk
  ca.src[2] = (const float*)d_in[7];  // Wv
  ca.src[3] = (const float*)d_in[9];  // Wo
  ca.src[4] = (const float*)d_in[0];  // query
  ca.src[5] = (const float*)d_in[1];  // key
  ca.src[6] = (const float*)d_in[2];  // value
  cvt_all<<<14336, 256, 0, stream>>>(ca, Wbf);

  qkv_gemm<<<dim3(Dn / 128, Mn / 128, 3), 256, 0, stream>>>(Xbf, Wbf, bq, bk, bv, QKV);
  flash_attn<<<dim3(Sn / 256, Bn * Hn, nsplit), 256, 0, stream>>>(QKV, QKV + MD, QKV + 2 * MD,
                                                                  Opart, Lpart);
  reduce_norm<<<Mn, 256, 0, stream>>>(Opart, Lpart, nsplit, Attn);
  out_gemm<<<dim3(Dn / 128, Mn / 128), 256, 0, stream>>>(Attn, Wbf + 3 * DD, bo, (float*)d_out);
}